// Round 1
// baseline (502.228 us; speedup 1.0000x reference)
//
#include <hip/hip_runtime.h>
#include <hip/hip_bf16.h>

// MoE head: router(top2 of 8) -> gather/compact -> GEMM1+GELU -> GEMM2 -> combine+residual+LN
// N=4096 tokens, H=1024, F=4096, E=8, TOP_K=2. bf16 MFMA compute, fp32 router/epilogues.

typedef unsigned short u16;
typedef unsigned int u32;
typedef __attribute__((ext_vector_type(4))) float f32x4;
typedef __attribute__((ext_vector_type(8))) short s16x8;

#define GLD16(gp, lp) __builtin_amdgcn_global_load_lds( \
    (const __attribute__((address_space(1))) void*)(gp), \
    (__attribute__((address_space(3))) void*)(lp), 16, 0, 0)

__device__ __forceinline__ u16 f2bf(float f) {
    union { float f; u32 u; } v; v.f = f;
    u32 u = v.u;
    return (u16)((u + 0x7fffu + ((u >> 16) & 1u)) >> 16);
}

// ---------------- K0: zero counts+cursors (16 ints) ----------------
__global__ void k_init(int* cc) { if (threadIdx.x < 16) cc[threadIdx.x] = 0; }

// ---------------- K1: router (fp32) + x->bf16 convert ----------------
// one wave per token; 1024 blocks x 256 threads
__global__ __launch_bounds__(256) void k_router(
    const float* __restrict__ x, const float* __restrict__ rw, const float* __restrict__ rb,
    u16* __restrict__ xb, int* __restrict__ eidx, float* __restrict__ wgt, int* __restrict__ counts)
{
    const int wav = threadIdx.x >> 6, lane = threadIdx.x & 63;
    const int t = blockIdx.x * 4 + wav;
    const float* xt = x + (size_t)t * 1024;
    float acc[8] = {0.f,0.f,0.f,0.f,0.f,0.f,0.f,0.f};
    #pragma unroll
    for (int c = 0; c < 4; c++) {
        const int base = c * 256 + lane * 4;
        const float4 xv = *(const float4*)(xt + base);
        ushort4 pk;
        pk.x = f2bf(xv.x); pk.y = f2bf(xv.y); pk.z = f2bf(xv.z); pk.w = f2bf(xv.w);
        *(ushort4*)(xb + (size_t)t * 1024 + base) = pk;
        #pragma unroll
        for (int e = 0; e < 8; e++) {
            const float4 wv = *(const float4*)(rw + e * 1024 + base);
            acc[e] += xv.x * wv.x + xv.y * wv.y + xv.z * wv.z + xv.w * wv.w;
        }
    }
    #pragma unroll
    for (int e = 0; e < 8; e++) {
        #pragma unroll
        for (int s = 32; s; s >>= 1) acc[e] += __shfl_xor(acc[e], s);
    }
    if (lane == 0) {
        float v0 = -3e38f, v1 = -3e38f; int i0 = 0, i1 = 0;
        #pragma unroll
        for (int e = 0; e < 8; e++) {
            const float l = acc[e] + rb[e];
            if (l > v0) { v1 = v0; i1 = i0; v0 = l; i0 = e; }
            else if (l > v1) { v1 = l; i1 = e; }
        }
        const float w0 = 1.0f / (1.0f + expf(v1 - v0));
        eidx[2 * t] = i0; eidx[2 * t + 1] = i1;
        wgt[2 * t] = w0; wgt[2 * t + 1] = 1.0f - w0;
        atomicAdd(&counts[i0], 1); atomicAdd(&counts[i1], 1);
    }
}

// ---------------- K2: exclusive prefix of 8 counts ----------------
__global__ void k_offsets(const int* __restrict__ counts, int* __restrict__ offsets) {
    if (threadIdx.x == 0) {
        int s = 0;
        for (int e = 0; e < 8; e++) { offsets[e] = s; s += counts[e]; }
        offsets[8] = s;
    }
}

// ---------------- K3: place assignments into compacted row list ----------------
__global__ __launch_bounds__(256) void k_place(
    const int* __restrict__ eidx, const int* __restrict__ offsets, int* __restrict__ cursors,
    int* __restrict__ rows, int* __restrict__ pos_of)
{
    const int a = blockIdx.x * 256 + threadIdx.x;   // 8192 assignments
    const int e = eidx[a];
    const int pos = offsets[e] + atomicAdd(&cursors[e], 1);
    rows[pos] = a >> 1;
    pos_of[a] = pos;
}

// ---------------- K4: transpose + fp32->bf16 convert (per expert) ----------------
// src [E][R][C] f32 -> dst [E][C][R] bf16 ; grid (C/32, R/32, E), block 256 (32x8)
__global__ __launch_bounds__(256) void k_transp(
    const float* __restrict__ src, u16* __restrict__ dst, int R, int C)
{
    __shared__ float tile[32][33];
    const int e = blockIdx.z;
    const float* s = src + (size_t)e * R * C;
    u16* d = dst + (size_t)e * R * C;
    const int c0 = blockIdx.x * 32, r0 = blockIdx.y * 32;
    const int tx = threadIdx.x & 31, ty = threadIdx.x >> 5;
    #pragma unroll
    for (int j = 0; j < 4; j++)
        tile[ty * 4 + j][tx] = s[(size_t)(r0 + ty * 4 + j) * C + c0 + tx];
    __syncthreads();
    #pragma unroll
    for (int j = 0; j < 4; j++)
        d[(size_t)(c0 + ty * 4 + j) * R + r0 + tx] = f2bf(tile[tx][ty * 4 + j]);
}

// ---------------- K5: grouped GEMM1 + bias + exact GELU -> h (bf16) ----------------
// A = gathered xb rows [cnt x 1024], B = W1t[e] [4096][1024] (n-major, k-contig)
// grid (F/128=32, 4096/128=32, E), block 256 (4 waves, 2x2 of 64x64)
__global__ __launch_bounds__(256) void k_gemm1(
    const u16* __restrict__ xb, const u16* __restrict__ W1t, const float* __restrict__ b1,
    u16* __restrict__ hbuf, const int* __restrict__ rows, const int* __restrict__ offsets)
{
    const int e = blockIdx.z;
    const int off = offsets[e], cnt = offsets[e + 1] - off;
    const int row0 = blockIdx.y * 128;
    if (row0 >= cnt) return;
    const int n0 = blockIdx.x * 128;
    const int tid = threadIdx.x;
    const int lane = tid & 63, wav = tid >> 6;

    __shared__ u16 At[128][32];
    __shared__ u16 Bt[128][32];

    const int ar0 = tid >> 2, ar1 = ar0 + 64;
    const int cl8 = (tid & 3) * 8;
    const int t0 = rows[off + min(row0 + ar0, cnt - 1)];
    const int t1 = rows[off + min(row0 + ar1, cnt - 1)];
    const u16* a_src0 = xb + (size_t)t0 * 1024 + cl8;
    const u16* a_src1 = xb + (size_t)t1 * 1024 + cl8;
    const u16* b_src0 = W1t + ((size_t)e * 4096 + n0 + ar0) * 1024 + cl8;
    const u16* b_src1 = W1t + ((size_t)e * 4096 + n0 + ar1) * 1024 + cl8;

    char* a_d0 = (char*)At + wav * 1024;
    char* a_d1 = (char*)At + 4096 + wav * 1024;
    char* b_d0 = (char*)Bt + wav * 1024;
    char* b_d1 = (char*)Bt + 4096 + wav * 1024;

    f32x4 acc[4][4] = {};
    const int wr = wav >> 1, wc = wav & 1;
    const int koff = (lane >> 4) * 8;
    const u16* Ab = &At[wr * 64 + (lane & 15)][koff];
    const u16* Bb = &Bt[wc * 64 + (lane & 15)][koff];

    for (int k0 = 0; k0 < 1024; k0 += 32) {
        GLD16(a_src0 + k0, a_d0);
        GLD16(a_src1 + k0, a_d1);
        GLD16(b_src0 + k0, b_d0);
        GLD16(b_src1 + k0, b_d1);
        __syncthreads();
        s16x8 af[4], bfr[4];
        #pragma unroll
        for (int i = 0; i < 4; i++) {
            af[i]  = *(const s16x8*)(Ab + i * 512);
            bfr[i] = *(const s16x8*)(Bb + i * 512);
        }
        #pragma unroll
        for (int mi = 0; mi < 4; mi++)
            #pragma unroll
            for (int ni = 0; ni < 4; ni++)
                acc[mi][ni] = __builtin_amdgcn_mfma_f32_16x16x32_bf16(af[mi], bfr[ni], acc[mi][ni], 0, 0, 0);
        __syncthreads();
    }

    const int rb4 = (lane >> 4) * 4;
    #pragma unroll
    for (int mi = 0; mi < 4; mi++) {
        #pragma unroll
        for (int j = 0; j < 4; j++) {
            const int lrow = wr * 64 + mi * 16 + rb4 + j;
            if (row0 + lrow < cnt) {
                const size_t gr = (size_t)(off + row0 + lrow);
                #pragma unroll
                for (int ni = 0; ni < 4; ni++) {
                    const int col = n0 + wc * 64 + ni * 16 + (lane & 15);
                    const float v = acc[mi][ni][j] + b1[e * 4096 + col];
                    const float g = 0.5f * v * (1.0f + erff(v * 0.70710678118654752f));
                    hbuf[gr * 4096 + col] = f2bf(g);
                }
            }
        }
    }
}

// ---------------- K6: grouped GEMM2 + bias -> y (fp32) ----------------
// A = h rows (contiguous compacted) [cnt x 4096], B = W2t[e] [1024][4096]
// grid (H/128=8, 4096/128=32, E), block 256
__global__ __launch_bounds__(256) void k_gemm2(
    const u16* __restrict__ hbuf, const u16* __restrict__ W2t, const float* __restrict__ b2,
    float* __restrict__ y, const int* __restrict__ offsets)
{
    const int e = blockIdx.z;
    const int off = offsets[e], cnt = offsets[e + 1] - off;
    const int row0 = blockIdx.y * 128;
    if (row0 >= cnt) return;
    const int n0 = blockIdx.x * 128;
    const int tid = threadIdx.x;
    const int lane = tid & 63, wav = tid >> 6;

    __shared__ u16 At[128][32];
    __shared__ u16 Bt[128][32];

    const int ar0 = tid >> 2, ar1 = ar0 + 64;
    const int cl8 = (tid & 3) * 8;
    const u16* a_src0 = hbuf + (size_t)(off + min(row0 + ar0, cnt - 1)) * 4096 + cl8;
    const u16* a_src1 = hbuf + (size_t)(off + min(row0 + ar1, cnt - 1)) * 4096 + cl8;
    const u16* b_src0 = W2t + ((size_t)e * 1024 + n0 + ar0) * 4096 + cl8;
    const u16* b_src1 = W2t + ((size_t)e * 1024 + n0 + ar1) * 4096 + cl8;

    char* a_d0 = (char*)At + wav * 1024;
    char* a_d1 = (char*)At + 4096 + wav * 1024;
    char* b_d0 = (char*)Bt + wav * 1024;
    char* b_d1 = (char*)Bt + 4096 + wav * 1024;

    f32x4 acc[4][4] = {};
    const int wr = wav >> 1, wc = wav & 1;
    const int koff = (lane >> 4) * 8;
    const u16* Ab = &At[wr * 64 + (lane & 15)][koff];
    const u16* Bb = &Bt[wc * 64 + (lane & 15)][koff];

    for (int k0 = 0; k0 < 4096; k0 += 32) {
        GLD16(a_src0 + k0, a_d0);
        GLD16(a_src1 + k0, a_d1);
        GLD16(b_src0 + k0, b_d0);
        GLD16(b_src1 + k0, b_d1);
        __syncthreads();
        s16x8 af[4], bfr[4];
        #pragma unroll
        for (int i = 0; i < 4; i++) {
            af[i]  = *(const s16x8*)(Ab + i * 512);
            bfr[i] = *(const s16x8*)(Bb + i * 512);
        }
        #pragma unroll
        for (int mi = 0; mi < 4; mi++)
            #pragma unroll
            for (int ni = 0; ni < 4; ni++)
                acc[mi][ni] = __builtin_amdgcn_mfma_f32_16x16x32_bf16(af[mi], bfr[ni], acc[mi][ni], 0, 0, 0);
        __syncthreads();
    }

    const int rb4 = (lane >> 4) * 4;
    #pragma unroll
    for (int mi = 0; mi < 4; mi++) {
        #pragma unroll
        for (int j = 0; j < 4; j++) {
            const int lrow = wr * 64 + mi * 16 + rb4 + j;
            if (row0 + lrow < cnt) {
                const size_t gr = (size_t)(off + row0 + lrow);
                #pragma unroll
                for (int ni = 0; ni < 4; ni++) {
                    const int col = n0 + wc * 64 + ni * 16 + (lane & 15);
                    y[gr * 1024 + col] = acc[mi][ni][j] + b2[e * 1024 + col];
                }
            }
        }
    }
}

// ---------------- K7: combine (w0*y0 + w1*y1 + residual) + LayerNorm ----------------
// one block (256 threads) per token
__global__ __launch_bounds__(256) void k_combine(
    const float* __restrict__ x, const float* __restrict__ y,
    const int* __restrict__ pos_of, const float* __restrict__ wgt,
    const float* __restrict__ gamma, const float* __restrict__ beta,
    float* __restrict__ out)
{
    const int t = blockIdx.x;
    const int tid = threadIdx.x;
    const int p0 = pos_of[2 * t], p1 = pos_of[2 * t + 1];
    const float w0 = wgt[2 * t], w1 = wgt[2 * t + 1];
    const int j4 = tid * 4;
    const float4 xv = *(const float4*)(x + (size_t)t * 1024 + j4);
    const float4 y0 = *(const float4*)(y + (size_t)p0 * 1024 + j4);
    const float4 y1 = *(const float4*)(y + (size_t)p1 * 1024 + j4);
    float a0 = xv.x + w0 * y0.x + w1 * y1.x;
    float a1 = xv.y + w0 * y0.y + w1 * y1.y;
    float a2 = xv.z + w0 * y0.z + w1 * y1.z;
    float a3 = xv.w + w0 * y0.w + w1 * y1.w;
    float s = a0 + a1 + a2 + a3;
    float q = a0 * a0 + a1 * a1 + a2 * a2 + a3 * a3;
    #pragma unroll
    for (int o = 32; o; o >>= 1) { s += __shfl_xor(s, o); q += __shfl_xor(q, o); }
    __shared__ float ls[4], lq[4];
    const int wav = tid >> 6, lane = tid & 63;
    if (lane == 0) { ls[wav] = s; lq[wav] = q; }
    __syncthreads();
    s = ls[0] + ls[1] + ls[2] + ls[3];
    q = lq[0] + lq[1] + lq[2] + lq[3];
    const float mu = s * (1.0f / 1024.0f);
    const float var = q * (1.0f / 1024.0f) - mu * mu;
    const float rs = rsqrtf(var + 1e-5f);
    const float4 g = *(const float4*)(gamma + j4);
    const float4 b = *(const float4*)(beta + j4);
    float4 o4;
    o4.x = (a0 - mu) * rs * g.x + b.x;
    o4.y = (a1 - mu) * rs * g.y + b.y;
    o4.z = (a2 - mu) * rs * g.z + b.z;
    o4.w = (a3 - mu) * rs * g.w + b.w;
    *(float4*)(out + (size_t)t * 1024 + j4) = o4;
}

extern "C" void kernel_launch(void* const* d_in, const int* in_sizes, int n_in,
                              void* d_out, int out_size, void* d_ws, size_t ws_size,
                              hipStream_t stream) {
    const float* x     = (const float*)d_in[0];   // [2,2048,1024]
    const float* rw    = (const float*)d_in[1];   // [8,1024]
    const float* rb    = (const float*)d_in[2];   // [8]
    const float* W1    = (const float*)d_in[3];   // [8,1024,4096]
    const float* b1    = (const float*)d_in[4];   // [8,4096]
    const float* W2    = (const float*)d_in[5];   // [8,4096,1024]
    const float* b2    = (const float*)d_in[6];   // [8,1024]
    const float* gamma = (const float*)d_in[7];   // [1024]
    const float* beta  = (const float*)d_in[8];   // [1024]
    float* out = (float*)d_out;

    // workspace carve (256B aligned)
    char* p = (char*)d_ws;
    auto alloc = [&](size_t bytes) { char* r = p; p += (bytes + 255) & ~(size_t)255; return r; };
    int*   counts  = (int*)alloc(16 * sizeof(int));      // counts[0..7], cursors[8..15]
    int*   cursors = counts + 8;
    int*   offsets = (int*)alloc(9 * sizeof(int));
    int*   eidx    = (int*)alloc(8192 * sizeof(int));
    float* wgt     = (float*)alloc(8192 * sizeof(float));
    int*   pos_of  = (int*)alloc(8192 * sizeof(int));
    int*   rows    = (int*)alloc(8192 * sizeof(int));
    u16*   xb      = (u16*)alloc((size_t)4096 * 1024 * 2);
    u16*   W1t     = (u16*)alloc((size_t)8 * 4096 * 1024 * 2);
    u16*   W2t     = (u16*)alloc((size_t)8 * 1024 * 4096 * 2);
    u16*   hbuf    = (u16*)alloc((size_t)8192 * 4096 * 2);
    float* y       = (float*)alloc((size_t)8192 * 1024 * 4);

    hipLaunchKernelGGL(k_init, dim3(1), dim3(64), 0, stream, counts);
    hipLaunchKernelGGL(k_router, dim3(1024), dim3(256), 0, stream, x, rw, rb, xb, eidx, wgt, counts);
    hipLaunchKernelGGL(k_offsets, dim3(1), dim3(64), 0, stream, counts, offsets);
    hipLaunchKernelGGL(k_place, dim3(32), dim3(256), 0, stream, eidx, offsets, cursors, rows, pos_of);
    // W1 [E][1024][4096] -> W1t [E][4096][1024]
    hipLaunchKernelGGL(k_transp, dim3(128, 32, 8), dim3(256), 0, stream, W1, W1t, 1024, 4096);
    // W2 [E][4096][1024] -> W2t [E][1024][4096]
    hipLaunchKernelGGL(k_transp, dim3(32, 128, 8), dim3(256), 0, stream, W2, W2t, 4096, 1024);
    hipLaunchKernelGGL(k_gemm1, dim3(32, 32, 8), dim3(256), 0, stream, xb, W1t, b1, hbuf, rows, offsets);
    hipLaunchKernelGGL(k_gemm2, dim3(8, 32, 8), dim3(256), 0, stream, hbuf, W2t, b2, y, offsets);
    hipLaunchKernelGGL(k_combine, dim3(4096), dim3(256), 0, stream, x, y, pos_of, wgt, gamma, beta, out);
}

// Round 2
// 473.067 us; speedup vs baseline: 1.0616x; 1.0616x over previous
//
#include <hip/hip_runtime.h>
#include <hip/hip_bf16.h>

// MoE head: router(top2 of 8) -> gather/compact -> GEMM1+GELU -> GEMM2(split-K) -> combine+residual+LN
// N=4096 tokens, H=1024, F=4096, E=8, TOP_K=2. bf16 MFMA compute, fp32 router/epilogues.

typedef unsigned short u16;
typedef unsigned int u32;
typedef __attribute__((ext_vector_type(4))) float f32x4;
typedef __attribute__((ext_vector_type(8))) short s16x8;
typedef __attribute__((ext_vector_type(8))) unsigned short u16x8;

#define GLD16(gp, lp) __builtin_amdgcn_global_load_lds( \
    (const __attribute__((address_space(1))) void*)(gp), \
    (__attribute__((address_space(3))) void*)(lp), 16, 0, 0)

__device__ __forceinline__ u16 f2bf(float f) {
    union { float f; u32 u; } v; v.f = f;
    u32 u = v.u;
    return (u16)((u + 0x7fffu + ((u >> 16) & 1u)) >> 16);
}

// fast GELU: 0.5v(1+tanh(0.79788456(v+0.044715v^3))) == v * sigmoid(2u)
__device__ __forceinline__ float gelu_f(float v) {
    const float u = v * (0.7978845608f + 0.0356774081f * v * v);
    const float t = __expf(-2.0f * u);
    return v * __builtin_amdgcn_rcpf(1.0f + t);
}

// ---------------- K0: zero counts+cursors (16 ints) ----------------
__global__ void k_init(int* cc) { if (threadIdx.x < 16) cc[threadIdx.x] = 0; }

// ---------------- K1: router (fp32) + x->bf16 convert ----------------
__global__ __launch_bounds__(256) void k_router(
    const float* __restrict__ x, const float* __restrict__ rw, const float* __restrict__ rb,
    u16* __restrict__ xb, int* __restrict__ eidx, float* __restrict__ wgt, int* __restrict__ counts)
{
    const int wav = threadIdx.x >> 6, lane = threadIdx.x & 63;
    const int t = blockIdx.x * 4 + wav;
    const float* xt = x + (size_t)t * 1024;
    float acc[8] = {0.f,0.f,0.f,0.f,0.f,0.f,0.f,0.f};
    #pragma unroll
    for (int c = 0; c < 4; c++) {
        const int base = c * 256 + lane * 4;
        const float4 xv = *(const float4*)(xt + base);
        ushort4 pk;
        pk.x = f2bf(xv.x); pk.y = f2bf(xv.y); pk.z = f2bf(xv.z); pk.w = f2bf(xv.w);
        *(ushort4*)(xb + (size_t)t * 1024 + base) = pk;
        #pragma unroll
        for (int e = 0; e < 8; e++) {
            const float4 wv = *(const float4*)(rw + e * 1024 + base);
            acc[e] += xv.x * wv.x + xv.y * wv.y + xv.z * wv.z + xv.w * wv.w;
        }
    }
    #pragma unroll
    for (int e = 0; e < 8; e++) {
        #pragma unroll
        for (int s = 32; s; s >>= 1) acc[e] += __shfl_xor(acc[e], s);
    }
    if (lane == 0) {
        float v0 = -3e38f, v1 = -3e38f; int i0 = 0, i1 = 0;
        #pragma unroll
        for (int e = 0; e < 8; e++) {
            const float l = acc[e] + rb[e];
            if (l > v0) { v1 = v0; i1 = i0; v0 = l; i0 = e; }
            else if (l > v1) { v1 = l; i1 = e; }
        }
        const float w0 = 1.0f / (1.0f + expf(v1 - v0));
        eidx[2 * t] = i0; eidx[2 * t + 1] = i1;
        wgt[2 * t] = w0; wgt[2 * t + 1] = 1.0f - w0;
        atomicAdd(&counts[i0], 1); atomicAdd(&counts[i1], 1);
    }
}

// ---------------- K2: exclusive prefix of 8 counts ----------------
__global__ void k_offsets(const int* __restrict__ counts, int* __restrict__ offsets) {
    if (threadIdx.x == 0) {
        int s = 0;
        for (int e = 0; e < 8; e++) { offsets[e] = s; s += counts[e]; }
        offsets[8] = s;
    }
}

// ---------------- K3: place assignments into compacted row list ----------------
__global__ __launch_bounds__(256) void k_place(
    const int* __restrict__ eidx, const int* __restrict__ offsets, int* __restrict__ cursors,
    int* __restrict__ rows, int* __restrict__ pos_of)
{
    const int a = blockIdx.x * 256 + threadIdx.x;   // 8192 assignments
    const int e = eidx[a];
    const int pos = offsets[e] + atomicAdd(&cursors[e], 1);
    rows[pos] = a >> 1;
    pos_of[a] = pos;
}

// ---------------- K4: transpose + fp32->bf16 (per expert), no LDS ----------------
// src [E][R][C] f32 -> dst [E][C][R] bf16 ; grid (C/64, R/32, E), block 256
// thread: one column c, 8 rows; 16B write, 64B contiguous per 4-lane group
__global__ __launch_bounds__(256) void k_transp(
    const float* __restrict__ src, u16* __restrict__ dst, int R, int C)
{
    const int e = blockIdx.z;
    const float* s = src + (size_t)e * R * C;
    u16* d = dst + (size_t)e * R * C;
    const int c = blockIdx.x * 64 + (threadIdx.x >> 2);
    const int r0 = blockIdx.y * 32 + (threadIdx.x & 3) * 8;
    u16x8 v;
    #pragma unroll
    for (int k = 0; k < 8; k++)
        v[k] = f2bf(s[(size_t)(r0 + k) * C + c]);
    *(u16x8*)(d + (size_t)c * R + r0) = v;
}

// ---------------- K5: grouped GEMM1 + bias + fast GELU -> h (bf16) ----------------
// grid (F/128=32, 4096/128=32, E), block 256 (4 waves, 2x2 of 64x64)
__global__ __launch_bounds__(256) void k_gemm1(
    const u16* __restrict__ xb, const u16* __restrict__ W1t, const float* __restrict__ b1,
    u16* __restrict__ hbuf, const int* __restrict__ rows, const int* __restrict__ offsets)
{
    const int e = blockIdx.z;
    const int off = offsets[e], cnt = offsets[e + 1] - off;
    const int row0 = blockIdx.y * 128;
    if (row0 >= cnt) return;
    const int n0 = blockIdx.x * 128;
    const int tid = threadIdx.x;
    const int lane = tid & 63, wav = tid >> 6;

    __shared__ u16 At[128][32];
    __shared__ u16 Bt[128][32];

    const int ar0 = tid >> 2, ar1 = ar0 + 64;
    const int cl8 = (tid & 3) * 8;
    const int t0 = rows[off + min(row0 + ar0, cnt - 1)];
    const int t1 = rows[off + min(row0 + ar1, cnt - 1)];
    const u16* a_src0 = xb + (size_t)t0 * 1024 + cl8;
    const u16* a_src1 = xb + (size_t)t1 * 1024 + cl8;
    const u16* b_src0 = W1t + ((size_t)e * 4096 + n0 + ar0) * 1024 + cl8;
    const u16* b_src1 = W1t + ((size_t)e * 4096 + n0 + ar1) * 1024 + cl8;

    char* a_d0 = (char*)At + wav * 1024;
    char* a_d1 = (char*)At + 4096 + wav * 1024;
    char* b_d0 = (char*)Bt + wav * 1024;
    char* b_d1 = (char*)Bt + 4096 + wav * 1024;

    f32x4 acc[4][4] = {};
    const int wr = wav >> 1, wc = wav & 1;
    const int koff = (lane >> 4) * 8;
    const u16* Ab = &At[wr * 64 + (lane & 15)][koff];
    const u16* Bb = &Bt[wc * 64 + (lane & 15)][koff];

    for (int k0 = 0; k0 < 1024; k0 += 32) {
        GLD16(a_src0 + k0, a_d0);
        GLD16(a_src1 + k0, a_d1);
        GLD16(b_src0 + k0, b_d0);
        GLD16(b_src1 + k0, b_d1);
        __syncthreads();
        s16x8 af[4], bfr[4];
        #pragma unroll
        for (int i = 0; i < 4; i++) {
            af[i]  = *(const s16x8*)(Ab + i * 512);
            bfr[i] = *(const s16x8*)(Bb + i * 512);
        }
        #pragma unroll
        for (int mi = 0; mi < 4; mi++)
            #pragma unroll
            for (int ni = 0; ni < 4; ni++)
                acc[mi][ni] = __builtin_amdgcn_mfma_f32_16x16x32_bf16(af[mi], bfr[ni], acc[mi][ni], 0, 0, 0);
        __syncthreads();
    }

    const int rb4 = (lane >> 4) * 4;
    #pragma unroll
    for (int mi = 0; mi < 4; mi++) {
        #pragma unroll
        for (int j = 0; j < 4; j++) {
            const int lrow = wr * 64 + mi * 16 + rb4 + j;
            if (row0 + lrow < cnt) {
                const size_t gr = (size_t)(off + row0 + lrow);
                #pragma unroll
                for (int ni = 0; ni < 4; ni++) {
                    const int col = n0 + wc * 64 + ni * 16 + (lane & 15);
                    const float v = acc[mi][ni][j] + b1[e * 4096 + col];
                    hbuf[gr * 4096 + col] = f2bf(gelu_f(v));
                }
            }
        }
    }
}

// ---------------- K6: grouped GEMM2 (split-K x2) + bias -> y0/y1 (fp32) ----------------
// grid (H/128=8, 4096/128=32, E*2), block 256; z = e*2 + kh
__global__ __launch_bounds__(256) void k_gemm2(
    const u16* __restrict__ hbuf, const u16* __restrict__ W2t, const float* __restrict__ b2,
    float* __restrict__ y0, float* __restrict__ y1, const int* __restrict__ offsets)
{
    const int e = blockIdx.z >> 1, kh = blockIdx.z & 1;
    const int off = offsets[e], cnt = offsets[e + 1] - off;
    const int row0 = blockIdx.y * 128;
    if (row0 >= cnt) return;
    const int n0 = blockIdx.x * 128;
    const int tid = threadIdx.x;
    const int lane = tid & 63, wav = tid >> 6;
    const int kbase = kh * 2048;

    __shared__ u16 At[128][32];
    __shared__ u16 Bt[128][32];

    const int ar0 = tid >> 2, ar1 = ar0 + 64;
    const int cl8 = (tid & 3) * 8;
    const u16* a_src0 = hbuf + (size_t)(off + min(row0 + ar0, cnt - 1)) * 4096 + kbase + cl8;
    const u16* a_src1 = hbuf + (size_t)(off + min(row0 + ar1, cnt - 1)) * 4096 + kbase + cl8;
    const u16* b_src0 = W2t + ((size_t)e * 1024 + n0 + ar0) * 4096 + kbase + cl8;
    const u16* b_src1 = W2t + ((size_t)e * 1024 + n0 + ar1) * 4096 + kbase + cl8;

    char* a_d0 = (char*)At + wav * 1024;
    char* a_d1 = (char*)At + 4096 + wav * 1024;
    char* b_d0 = (char*)Bt + wav * 1024;
    char* b_d1 = (char*)Bt + 4096 + wav * 1024;

    f32x4 acc[4][4] = {};
    const int wr = wav >> 1, wc = wav & 1;
    const int koff = (lane >> 4) * 8;
    const u16* Ab = &At[wr * 64 + (lane & 15)][koff];
    const u16* Bb = &Bt[wc * 64 + (lane & 15)][koff];

    for (int k0 = 0; k0 < 2048; k0 += 32) {
        GLD16(a_src0 + k0, a_d0);
        GLD16(a_src1 + k0, a_d1);
        GLD16(b_src0 + k0, b_d0);
        GLD16(b_src1 + k0, b_d1);
        __syncthreads();
        s16x8 af[4], bfr[4];
        #pragma unroll
        for (int i = 0; i < 4; i++) {
            af[i]  = *(const s16x8*)(Ab + i * 512);
            bfr[i] = *(const s16x8*)(Bb + i * 512);
        }
        #pragma unroll
        for (int mi = 0; mi < 4; mi++)
            #pragma unroll
            for (int ni = 0; ni < 4; ni++)
                acc[mi][ni] = __builtin_amdgcn_mfma_f32_16x16x32_bf16(af[mi], bfr[ni], acc[mi][ni], 0, 0, 0);
        __syncthreads();
    }

    float* y = kh ? y1 : y0;
    const int rb4 = (lane >> 4) * 4;
    #pragma unroll
    for (int mi = 0; mi < 4; mi++) {
        #pragma unroll
        for (int j = 0; j < 4; j++) {
            const int lrow = wr * 64 + mi * 16 + rb4 + j;
            if (row0 + lrow < cnt) {
                const size_t gr = (size_t)(off + row0 + lrow);
                #pragma unroll
                for (int ni = 0; ni < 4; ni++) {
                    const int col = n0 + wc * 64 + ni * 16 + (lane & 15);
                    const float bias = kh ? 0.f : b2[e * 1024 + col];
                    y[gr * 1024 + col] = acc[mi][ni][j] + bias;
                }
            }
        }
    }
}

// ---------------- K7: combine (w0*(y0+y1) + residual) + LayerNorm ----------------
__global__ __launch_bounds__(256) void k_combine(
    const float* __restrict__ x, const float* __restrict__ y0, const float* __restrict__ y1,
    const int* __restrict__ pos_of, const float* __restrict__ wgt,
    const float* __restrict__ gamma, const float* __restrict__ beta,
    float* __restrict__ out)
{
    const int t = blockIdx.x;
    const int tid = threadIdx.x;
    const int p0 = pos_of[2 * t], p1 = pos_of[2 * t + 1];
    const float w0 = wgt[2 * t], w1 = wgt[2 * t + 1];
    const int j4 = tid * 4;
    const float4 xv = *(const float4*)(x + (size_t)t * 1024 + j4);
    const float4 ya0 = *(const float4*)(y0 + (size_t)p0 * 1024 + j4);
    const float4 yb0 = *(const float4*)(y1 + (size_t)p0 * 1024 + j4);
    const float4 ya1 = *(const float4*)(y0 + (size_t)p1 * 1024 + j4);
    const float4 yb1 = *(const float4*)(y1 + (size_t)p1 * 1024 + j4);
    float a0 = xv.x + w0 * (ya0.x + yb0.x) + w1 * (ya1.x + yb1.x);
    float a1 = xv.y + w0 * (ya0.y + yb0.y) + w1 * (ya1.y + yb1.y);
    float a2 = xv.z + w0 * (ya0.z + yb0.z) + w1 * (ya1.z + yb1.z);
    float a3 = xv.w + w0 * (ya0.w + yb0.w) + w1 * (ya1.w + yb1.w);
    float s = a0 + a1 + a2 + a3;
    float q = a0 * a0 + a1 * a1 + a2 * a2 + a3 * a3;
    #pragma unroll
    for (int o = 32; o; o >>= 1) { s += __shfl_xor(s, o); q += __shfl_xor(q, o); }
    __shared__ float ls[4], lq[4];
    const int wav = tid >> 6, lane = tid & 63;
    if (lane == 0) { ls[wav] = s; lq[wav] = q; }
    __syncthreads();
    s = ls[0] + ls[1] + ls[2] + ls[3];
    q = lq[0] + lq[1] + lq[2] + lq[3];
    const float mu = s * (1.0f / 1024.0f);
    const float var = q * (1.0f / 1024.0f) - mu * mu;
    const float rs = rsqrtf(var + 1e-5f);
    const float4 g = *(const float4*)(gamma + j4);
    const float4 b = *(const float4*)(beta + j4);
    float4 o4;
    o4.x = (a0 - mu) * rs * g.x + b.x;
    o4.y = (a1 - mu) * rs * g.y + b.y;
    o4.z = (a2 - mu) * rs * g.z + b.z;
    o4.w = (a3 - mu) * rs * g.w + b.w;
    *(float4*)(out + (size_t)t * 1024 + j4) = o4;
}

extern "C" void kernel_launch(void* const* d_in, const int* in_sizes, int n_in,
                              void* d_out, int out_size, void* d_ws, size_t ws_size,
                              hipStream_t stream) {
    const float* x     = (const float*)d_in[0];   // [2,2048,1024]
    const float* rw    = (const float*)d_in[1];   // [8,1024]
    const float* rb    = (const float*)d_in[2];   // [8]
    const float* W1    = (const float*)d_in[3];   // [8,1024,4096]
    const float* b1    = (const float*)d_in[4];   // [8,4096]
    const float* W2    = (const float*)d_in[5];   // [8,4096,1024]
    const float* b2    = (const float*)d_in[6];   // [8,1024]
    const float* gamma = (const float*)d_in[7];   // [1024]
    const float* beta  = (const float*)d_in[8];   // [1024]
    float* out = (float*)d_out;

    // workspace carve (256B aligned)
    char* p = (char*)d_ws;
    auto alloc = [&](size_t bytes) { char* r = p; p += (bytes + 255) & ~(size_t)255; return r; };
    int*   counts  = (int*)alloc(16 * sizeof(int));      // counts[0..7], cursors[8..15]
    int*   cursors = counts + 8;
    int*   offsets = (int*)alloc(9 * sizeof(int));
    int*   eidx    = (int*)alloc(8192 * sizeof(int));
    float* wgt     = (float*)alloc(8192 * sizeof(float));
    int*   pos_of  = (int*)alloc(8192 * sizeof(int));
    int*   rows    = (int*)alloc(8192 * sizeof(int));
    u16*   xb      = (u16*)alloc((size_t)4096 * 1024 * 2);
    u16*   W1t     = (u16*)alloc((size_t)8 * 4096 * 1024 * 2);   // 64MB; dead after gemm1
    u16*   W2t     = (u16*)alloc((size_t)8 * 1024 * 4096 * 2);
    u16*   hbuf    = (u16*)alloc((size_t)8192 * 4096 * 2);
    // y0/y1 alias W1t (64MB = 2 x 32MB): W1t is consumed by gemm1 before gemm2 writes y
    float* y0 = (float*)W1t;
    float* y1 = y0 + (size_t)8192 * 1024;

    hipLaunchKernelGGL(k_init, dim3(1), dim3(64), 0, stream, counts);
    hipLaunchKernelGGL(k_router, dim3(1024), dim3(256), 0, stream, x, rw, rb, xb, eidx, wgt, counts);
    hipLaunchKernelGGL(k_offsets, dim3(1), dim3(64), 0, stream, counts, offsets);
    hipLaunchKernelGGL(k_place, dim3(32), dim3(256), 0, stream, eidx, offsets, cursors, rows, pos_of);
    // W1 [E][1024][4096] -> W1t [E][4096][1024]
    hipLaunchKernelGGL(k_transp, dim3(64, 32, 8), dim3(256), 0, stream, W1, W1t, 1024, 4096);
    // W2 [E][4096][1024] -> W2t [E][1024][4096]
    hipLaunchKernelGGL(k_transp, dim3(16, 128, 8), dim3(256), 0, stream, W2, W2t, 4096, 1024);
    hipLaunchKernelGGL(k_gemm1, dim3(32, 32, 8), dim3(256), 0, stream, xb, W1t, b1, hbuf, rows, offsets);
    hipLaunchKernelGGL(k_gemm2, dim3(8, 32, 16), dim3(256), 0, stream, hbuf, W2t, b2, y0, y1, offsets);
    hipLaunchKernelGGL(k_combine, dim3(4096), dim3(256), 0, stream, x, y0, y1, pos_of, wgt, gamma, beta, out);
}